// Round 24
// baseline (101.034 us; speedup 1.0000x reference)
//
#include <hip/hip_runtime.h>

// RAFT corr block: B=2, D=256, H=W=80, 4 levels, radius 4.
// avg_pool2(corr) over fmap2's spatial dims == corr with avg-pooled fmap2.
// R24: counted-vmcnt pipeline (T4). Per wave: two 4KB stage buffers (4 planes
// each); issue B0,B1 -> loop{ vmcnt(4) -> compute oldest -> issue into freed }.
// Never drains vmcnt to 0 in the steady loop; 48KB LDS -> 3 blocks/CU.

typedef _Float16 h2 __attribute__((ext_vector_type(2)));
typedef _Float16 half8 __attribute__((ext_vector_type(8)));
typedef float f32x4 __attribute__((ext_vector_type(4)));

#define HWDIM 80
#define DCH 256
#define NPIX 12800
#define NBUCKET 800
#define CHP 352              // padded channel stride in scratch

// ---------- zero fill ----------
__global__ __launch_bounds__(256) void zero_k(float4* __restrict__ dst) {
    int i = blockIdx.x * 256 + threadIdx.x;
    dst[i] = make_float4(0.f, 0.f, 0.f, 0.f);
}

// ---------- fused transpose: f1 -> spatial-major f16; f2 -> K-plane padded ----------
__global__ __launch_bounds__(256) void transpose_all(const float* __restrict__ f1,
                                                     const float* __restrict__ f2,
                                                     _Float16* __restrict__ f1h,
                                                     _Float16* __restrict__ f2p0) {
    __shared__ float tile[256][33];
    int bid = blockIdx.x;
    bool isf1 = bid < 400;
    int lb = isf1 ? bid : bid - 400;
    const float* src = isf1 ? f1 : f2;
    int b = lb / 200;
    int s0 = (lb % 200) * 32;
    int t = threadIdx.x;
    const float* sb = src + (size_t)b * DCH * (HWDIM * HWDIM);
#pragma unroll 4
    for (int k = 0; k < 32; ++k) {
        int j = t + 256 * k;
        int c = j >> 5, s = j & 31;
        tile[c][s] = sb[(size_t)c * (HWDIM * HWDIM) + s0 + s];
    }
    __syncthreads();
    int p = t & 127;
    int srow = t >> 7;
    if (isf1) {
        _Float16* db = f1h + ((size_t)b * 6400 + s0) * DCH;
#pragma unroll 4
        for (int k = 0; k < 16; ++k) {
            int s = 2 * k + srow;
            h2 v;
            v[0] = (_Float16)tile[2 * p][s];
            v[1] = (_Float16)tile[2 * p + 1][s];
            *(h2*)(db + (size_t)s * DCH + 2 * p) = v;
        }
    } else {
#pragma unroll 4
        for (int k = 0; k < 16; ++k) {
            int s = 2 * k + srow;
            int spatial = s0 + s;
            int yy = spatial / 80;
            int xx = spatial - yy * 80;
            h2 v;
            v[0] = (_Float16)tile[2 * p][s];
            v[1] = (_Float16)tile[2 * p + 1][s];
            size_t off = (size_t)b * 2073600 + (size_t)(p >> 4) * 259200
                       + ((size_t)(yy + 5) * 90 + (xx + 5)) * 32 + ((2 * p) & 31);
            *(h2*)(f2p0 + off) = v;
        }
    }
}

// ---------- all pools from L0 directly: L1 2x2, L2 4x4, L3 8x8 ----------
__global__ __launch_bounds__(256) void pools(const _Float16* __restrict__ l0,
                                             _Float16* __restrict__ l1,
                                             _Float16* __restrict__ l2,
                                             _Float16* __restrict__ l3) {
    int i = blockIdx.x * 256 + threadIdx.x;      // 409600 + 102400 + 25600 = 537600
    if (i < 409600) {
        int c2 = i & 15;
        int r = i >> 4;
        int x = r % 40; r /= 40;
        int y = r % 40; r /= 40;
        int pl = r & 7;
        int b = r >> 3;
        const h2* s = (const h2*)l0 + (size_t)b * 1036800 + (size_t)pl * 129600
                    + ((size_t)(2 * y + 5) * 90 + (2 * x + 5)) * 16 + c2;
        h2 v00 = s[0], v01 = s[16], v10 = s[90 * 16], v11 = s[90 * 16 + 16];
        float r0 = ((float)v00[0] + (float)v01[0] + (float)v10[0] + (float)v11[0]) * 0.25f;
        float r1 = ((float)v00[1] + (float)v01[1] + (float)v10[1] + (float)v11[1]) * 0.25f;
        h2 o; o[0] = (_Float16)r0; o[1] = (_Float16)r1;
        *((h2*)l1 + (size_t)b * 320000 + (size_t)pl * 40000
          + ((size_t)(y + 5) * 50 + (x + 5)) * 16 + c2) = o;
    } else if (i < 512000) {
        int j = i - 409600;
        int c2 = j & 15;
        int r = j >> 4;
        int x = r % 20; r /= 20;
        int y = r % 20; r /= 20;
        int pl = r & 7;
        int b = r >> 3;
        const h2* s = (const h2*)l0 + (size_t)b * 1036800 + (size_t)pl * 129600 + c2;
        float r0 = 0.f, r1 = 0.f;
#pragma unroll
        for (int dy = 0; dy < 4; ++dy)
#pragma unroll
            for (int dx = 0; dx < 4; ++dx) {
                h2 v = s[((size_t)(4 * y + dy + 5) * 90 + (4 * x + dx + 5)) * 16];
                r0 += (float)v[0];
                r1 += (float)v[1];
            }
        h2 o; o[0] = (_Float16)(r0 * 0.0625f); o[1] = (_Float16)(r1 * 0.0625f);
        *((h2*)l2 + (size_t)b * 115200 + (size_t)pl * 14400
          + ((size_t)(y + 5) * 30 + (x + 5)) * 16 + c2) = o;
    } else {
        int j = i - 512000;
        int c2 = j & 15;
        int r = j >> 4;
        int x = r % 10; r /= 10;
        int y = r % 10; r /= 10;
        int pl = r & 7;
        int b = r >> 3;
        const h2* s = (const h2*)l0 + (size_t)b * 1036800 + (size_t)pl * 129600 + c2;
        float r0 = 0.f, r1 = 0.f;
#pragma unroll
        for (int dy = 0; dy < 8; ++dy)
#pragma unroll
            for (int dx = 0; dx < 8; ++dx) {
                h2 v = s[((size_t)(8 * y + dy + 5) * 90 + (8 * x + dx + 5)) * 16];
                r0 += (float)v[0];
                r1 += (float)v[1];
            }
        h2 o; o[0] = (_Float16)(r0 * 0.015625f); o[1] = (_Float16)(r1 * 0.015625f);
        *((h2*)l3 + (size_t)b * 51200 + (size_t)pl * 6400
          + ((size_t)(y + 5) * 20 + (x + 5)) * 16 + c2) = o;
    }
}

// ---------- single-block bucket sort (4x4 cells, pad 16) ----------
static __device__ __forceinline__ int bucket_of(const float* coords, int n) {
    int b = n / 6400;
    int r = n - b * 6400;
    float cx = coords[(size_t)b * 12800 + r];
    float cy = coords[(size_t)b * 12800 + 6400 + r];
    int ix = min(max((int)floorf(cx), 0), 79);
    int iy = min(max((int)floorf(cy), 0), 79);
    return b * 400 + (iy >> 2) * 20 + (ix >> 2);
}

__global__ __launch_bounds__(1024) void bucket_k(const float* __restrict__ coords,
                                                 int* __restrict__ sortedIdxP,
                                                 int* __restrict__ rank) {
    __shared__ unsigned int histS[NBUCKET], startS[NBUCKET], curS[NBUCKET];
    __shared__ unsigned int waveSum[16];
    __shared__ unsigned int totalS;
    int t = threadIdx.x;
    if (t < NBUCKET) histS[t] = 0u;
    __syncthreads();
    int bkt[13];
#pragma unroll
    for (int i = 0; i < 13; ++i) {
        int n = i * 1024 + t;
        if (n < NPIX) {
            bkt[i] = bucket_of(coords, n);
            atomicAdd(&histS[bkt[i]], 1u);
        }
    }
    __syncthreads();
    unsigned int v = (t < NBUCKET) ? ((histS[t] + 15u) & ~15u) : 0u;
    unsigned int x = v;
#pragma unroll
    for (int d = 1; d < 64; d <<= 1) {
        unsigned int y = __shfl_up(x, d);
        if ((t & 63) >= d) x += y;
    }
    if ((t & 63) == 63) waveSum[t >> 6] = x;
    __syncthreads();
    if (t < 16) {
        unsigned int w = waveSum[t];
#pragma unroll
        for (int d = 1; d < 16; d <<= 1) {
            unsigned int y = __shfl_up(w, d);
            if (t >= d) w += y;
        }
        waveSum[t] = w;
    }
    __syncthreads();
    unsigned int incl = x + ((t >> 6) ? waveSum[(t >> 6) - 1] : 0u);
    if (t < NBUCKET) {
        unsigned int e = incl - v;
        startS[t] = e;
        curS[t] = e;
        if (t == NBUCKET - 1) totalS = incl;
    }
    __syncthreads();
#pragma unroll
    for (int i = 0; i < 13; ++i) {
        int n = i * 1024 + t;
        if (n < NPIX) {
            unsigned int pos = atomicAdd(&curS[bkt[i]], 1u);
            sortedIdxP[pos] = n;
            rank[n] = (int)pos;
        }
    }
    __syncthreads();
    if (t < NBUCKET) {
        unsigned int h = histS[t];
        if (h) {
            unsigned int pc = (h + 15u) & ~15u;
            unsigned int base = startS[t];
            int dup = sortedIdxP[base];
            for (unsigned int s = h; s < pc; ++s) sortedIdxP[base + s] = dup;
        }
    }
    for (unsigned int s = totalS + t; s < 25600u; s += 1024u) sortedIdxP[s] = -1;
}

// ---------- one pyramid level: per-wave counted-vmcnt pipelined tiles ----------
template <int L>
static __device__ __forceinline__ void run_level(
    int tid, int lane, int wave, int b,
    const _Float16* __restrict__ f2pL,
    const int* X0cS, const int* Y0cS,
    const float (*fxS)[16], const float (*fyS)[16],
    const int (*lxS)[16], const int (*lyS)[16],
    const half8* bf, char* wbuf, _Float16* G,
    _Float16* __restrict__ sc) {
    const int Ww = L == 0 ? 13 : L == 1 ? 11 : 10;
    const int NT = L == 0 ? 11 : L == 1 ? 8 : 7;
    const int MT = L == 0 ? 169 : L == 1 ? 121 : 100;
    const int MAG = L == 0 ? 161320 : L == 1 ? 190652 : 209716;
    const int Wp = L == 0 ? 90 : L == 1 ? 50 : L == 2 ? 30 : 20;
    const int PSB = 2 * (L == 0 ? 259200 : L == 1 ? 80000 : L == 2 ? 28800 : 12800);
    const int PB = L == 0 ? 2073600 : L == 1 ? 640000 : L == 2 ? 230400 : 102400;
    const _Float16* f2b = f2pL + (size_t)b * PB
                        + ((size_t)(Y0cS[L] + 5) * Wp + (X0cS[L] + 5)) * 32;
    int rr = lane & 15;
    int ch = lane >> 4;
    int ntw = (NT - wave + 3) >> 2;          // tiles for this wave (wave<4<=NT)
    int nb = ntw * 2;                         // 4-plane batches

    // batch j: tile = wave + (j>>1)*4, planes (j&1)*4 .. +3
    auto issue = [&](int j, char* buf) {
        int t = wave + (j >> 1) * 4;
        int h = j & 1;
        int r = min(t * 16 + rr, MT - 1);
        int my = (r * MAG) >> 21;
        int mx = r - my * Ww;
        const char* g0 = (const char*)f2b + (my * Wp + mx) * 64 + ch * 16
                       + h * 4 * PSB;
#pragma unroll
        for (int kk = 0; kk < 4; ++kk)
            __builtin_amdgcn_global_load_lds(
                (const __attribute__((address_space(1))) void*)(g0 + kk * PSB),
                (__attribute__((address_space(3))) void*)(buf + kk * 1024), 16, 0, 0);
    };

    issue(0, wbuf);
    if (nb > 1) issue(1, wbuf + 4096);
    f32x4 acc = {0.f, 0.f, 0.f, 0.f};
    for (int j = 0; j < nb; ++j) {
        char* buf = wbuf + (j & 1) * 4096;
        if (j + 1 < nb) asm volatile("s_waitcnt vmcnt(4)" ::: "memory");
        else            asm volatile("s_waitcnt vmcnt(0)" ::: "memory");
        __builtin_amdgcn_sched_barrier(0);
        if ((j & 1) == 0) {
#pragma unroll
            for (int kk = 0; kk < 4; ++kk) {
                half8 a = *(const half8*)(buf + kk * 1024 + lane * 16);
                acc = __builtin_amdgcn_mfma_f32_16x16x32_f16(a, bf[kk], acc, 0, 0, 0);
            }
        } else {
#pragma unroll
            for (int kk = 0; kk < 4; ++kk) {
                half8 a = *(const half8*)(buf + kk * 1024 + lane * 16);
                acc = __builtin_amdgcn_mfma_f32_16x16x32_f16(a, bf[4 + kk], acc, 0, 0, 0);
            }
        }
        if (j + 2 < nb) issue(j + 2, buf);
        if (j & 1) {                          // tile finished -> write G
            int t = wave + (j >> 1) * 4;
            int gr = t * 16 + ch * 4;
#pragma unroll
            for (int q = 0; q < 4; ++q)
                G[(gr + q) * 17 + rr] = (_Float16)acc[q];
            acc[0] = 0.f; acc[1] = 0.f; acc[2] = 0.f; acc[3] = 0.f;
        }
    }
    __syncthreads();
    // epilogue for this level: 16 px x 81 taps
    for (int idx = tid; idx < 16 * 81; idx += 256) {
        int x = (idx * 12946) >> 20;          // idx/81, exact
        int k = idx - x * 81;
        int a = (k * 57) >> 9;                // k/9
        int c = k - 9 * a;
        int gx = lxS[L][x] + a, gy = lyS[L][x] + c;
        int m00 = gy * Ww + gx;
        float fx = fxS[L][x], fy = fyS[L][x];
        float t00 = (float)G[m00 * 17 + x];
        float t01 = (float)G[(m00 + 1) * 17 + x];
        float t10 = (float)G[(m00 + Ww) * 17 + x];
        float t11 = (float)G[(m00 + Ww + 1) * 17 + x];
        float v = ((1.f - fy) * ((1.f - fx) * t00 + fx * t01)
                 + fy * ((1.f - fx) * t10 + fx * t11)) * 0.0625f;
        sc[x * CHP + L * 81 + k] = (_Float16)v;
    }
    __syncthreads();       // protect G reuse by next level
}

// ---------- main: 256 threads / 4 waves, pipelined staging ----------
__global__ __launch_bounds__(256, 3) void corr_mfma(
    const _Float16* __restrict__ f1h,
    const _Float16* __restrict__ f2p0, const _Float16* __restrict__ f2p1,
    const _Float16* __restrict__ f2p2, const _Float16* __restrict__ f2p3,
    const float* __restrict__ coords, const int* __restrict__ sortedIdxP,
    _Float16* __restrict__ scratch) {
    __shared__ __align__(16) char stageB[4][8192];   // 32 KB: 2x4KB per wave
    __shared__ _Float16 G[176 * 17];                 //  6.0 KB
    __shared__ _Float16 f1S[16 * 264];               //  8.25 KB
    __shared__ float fxS[4][16], fyS[4][16];
    __shared__ int lxS[4][16], lyS[4][16];
    __shared__ int X0cS[4], Y0cS[4], bS;

    int pphys = blockIdx.x;
    int l = (pphys & 7) * 200 + (pphys >> 3);   // XCD swizzle, 1600 % 8 == 0
    int tid = threadIdx.x;
    if (sortedIdxP[l * 16] < 0) return;
    int lane = tid & 63;
    int wave = tid >> 6;

    // stage f1 block: 16 px x 512 B = 512 float4s over 256 threads
#pragma unroll
    for (int uu = 0; uu < 2; ++uu) {
        int u = tid + uu * 256;
        int px = u >> 5, q = u & 31;
        int n = sortedIdxP[l * 16 + px];
        const float4* src = (const float4*)(f1h + (size_t)n * DCH);
        *((float4*)(f1S + px * 264) + q) = src[q];
    }
    if (tid < 64) {
        int px = tid & 15, Lt = tid >> 4;
        int n = sortedIdxP[l * 16 + px];
        int b = n / 6400;
        int r = n - b * 6400;
        float cx = coords[(size_t)b * 12800 + r];
        float cy = coords[(size_t)b * 12800 + 6400 + r];
        float ls = 1.0f / (float)(1 << Lt);
        float cxl = cx * ls, cyl = cy * ls;
        float fxf = floorf(cxl), fyf = floorf(cyl);
        int X0 = (int)fxf - 4, Y0 = (int)fyf - 4;
        int ix = min(max((int)floorf(cx), 0), 79);
        int iy = min(max((int)floorf(cy), 0), 79);
        int X0c = (((ix >> 2) * 4) >> Lt) - 4;
        int Y0c = (((iy >> 2) * 4) >> Lt) - 4;
        lxS[Lt][px] = min(max(X0 - X0c, 0), 3);
        lyS[Lt][px] = min(max(Y0 - Y0c, 0), 3);
        fxS[Lt][px] = cxl - fxf;
        fyS[Lt][px] = cyl - fyf;
        X0cS[Lt] = X0c;
        Y0cS[Lt] = Y0c;
        if (tid == 0) bS = sortedIdxP[l * 16] / 6400;
    }
    __syncthreads();
    int b = bS;
    _Float16* sc = scratch + (size_t)l * 16 * CHP;
    char* wbuf = stageB[wave];

    // hoist this wave's B fragments from LDS
    half8 bf[8];
#pragma unroll
    for (int kk = 0; kk < 8; ++kk)
        bf[kk] = *(const half8*)(f1S + (lane & 15) * 264 + ((lane >> 4) + 4 * kk) * 8);

    run_level<0>(tid, lane, wave, b, f2p0, X0cS, Y0cS, fxS, fyS, lxS, lyS, bf, wbuf, G, sc);
    run_level<1>(tid, lane, wave, b, f2p1, X0cS, Y0cS, fxS, fyS, lxS, lyS, bf, wbuf, G, sc);
    run_level<2>(tid, lane, wave, b, f2p2, X0cS, Y0cS, fxS, fyS, lxS, lyS, bf, wbuf, G, sc);
    run_level<3>(tid, lane, wave, b, f2p3, X0cS, Y0cS, fxS, fyS, lxS, lyS, bf, wbuf, G, sc);
}

// ---------- unsort: gather full 64B lines, LDS transpose, coalesced writes ----
__global__ __launch_bounds__(256) void unsort_t(const _Float16* __restrict__ scratch,
                                                const int* __restrict__ rank,
                                                float* __restrict__ out) {
    __shared__ _Float16 lds[64][40];
    int blk = blockIdx.x;
    int b = blk / 100;
    int nl0 = (blk % 100) * 64;
    int t = threadIdx.x;
    int p = t >> 2, j = t & 3;
    int n = blk * 64 + p;
    int rk = rank[n];
    const float4* src = (const float4*)(scratch + (size_t)rk * CHP);
    int px = t & 63, iq = t >> 6;

    for (int c = 0; c < 11; ++c) {
        float4 f4 = src[c * 4 + j];
        *(float4*)(&lds[p][j * 8]) = f4;
        __syncthreads();
#pragma unroll
        for (int w = 0; w < 8; ++w) {
            int i = w * 4 + iq;
            int ch = c * 32 + i;
            if (ch < 324)
                out[((size_t)b * 324 + ch) * 6400 + nl0 + px] = (float)lds[px][i];
        }
        __syncthreads();
    }
}

extern "C" void kernel_launch(void* const* d_in, const int* in_sizes, int n_in,
                              void* d_out, int out_size, void* d_ws, size_t ws_size,
                              hipStream_t stream) {
    const float* fmap1 = (const float*)d_in[0];
    const float* fmap2 = (const float*)d_in[1];
    const float* coords = (const float*)d_in[2];
    float* out = (float*)d_out;
    char* ws = (char*)d_ws;

    _Float16* f1h  = (_Float16*)(ws);                  //  6,553,600
    _Float16* f2p0 = (_Float16*)(ws + 6553600);        //  8,294,400 (K-plane, pad 5)
    _Float16* f2p1 = (_Float16*)(ws + 14848000);       //  2,560,000
    _Float16* f2p2 = (_Float16*)(ws + 17408000);       //    921,600
    _Float16* f2p3 = (_Float16*)(ws + 18329600);       //    409,600
    int* sortedIdxP = (int*)(ws + 18739200);           //    102,400 (25600 ints)
    int* rank       = (int*)(ws + 18841600);           //     51,200
    _Float16* scratch = (_Float16*)(ws + 18892800);    // 25600*352*2 = 18,022,400

    zero_k<<<dim3(2975), dim3(256), 0, stream>>>((float4*)f2p0);

    transpose_all<<<dim3(800), dim3(256), 0, stream>>>(fmap1, fmap2, f1h, f2p0);
    pools<<<dim3(2100), dim3(256), 0, stream>>>(f2p0, f2p1, f2p2, f2p3);
    bucket_k<<<dim3(1), dim3(1024), 0, stream>>>(coords, sortedIdxP, rank);
    corr_mfma<<<dim3(1600), dim3(256), 0, stream>>>(f1h, f2p0, f2p1, f2p2, f2p3,
                                                    coords, sortedIdxP, scratch);
    unsort_t<<<dim3(200), dim3(256), 0, stream>>>(scratch, rank, out);
}

// Round 26
// 90.837 us; speedup vs baseline: 1.1122x; 1.1122x over previous
//
#include <hip/hip_runtime.h>

// RAFT corr block: B=2, D=256, H=W=80, 4 levels, radius 4.
// avg_pool2(corr) over fmap2's spatial dims == corr with avg-pooled fmap2.
// R26 (final): exact revert to R20 champion (90.88us). R25's zero+transpose
// fusion raced (zero covers interiors too; ordering only held across
// dispatches). Separate zero_k dispatch restores correctness.

typedef _Float16 h2 __attribute__((ext_vector_type(2)));
typedef _Float16 half8 __attribute__((ext_vector_type(8)));
typedef float f32x4 __attribute__((ext_vector_type(4)));

#define HWDIM 80
#define DCH 256
#define NPIX 12800
#define NBUCKET 800
#define CHP 352              // padded channel stride in scratch

// ---------- zero fill ----------
__global__ __launch_bounds__(256) void zero_k(float4* __restrict__ dst) {
    int i = blockIdx.x * 256 + threadIdx.x;
    dst[i] = make_float4(0.f, 0.f, 0.f, 0.f);
}

// ---------- fused transpose: f1 -> spatial-major f16; f2 -> K-plane padded ----------
__global__ __launch_bounds__(256) void transpose_all(const float* __restrict__ f1,
                                                     const float* __restrict__ f2,
                                                     _Float16* __restrict__ f1h,
                                                     _Float16* __restrict__ f2p0) {
    __shared__ float tile[256][33];
    int bid = blockIdx.x;
    bool isf1 = bid < 400;
    int lb = isf1 ? bid : bid - 400;
    const float* src = isf1 ? f1 : f2;
    int b = lb / 200;
    int s0 = (lb % 200) * 32;
    int t = threadIdx.x;
    const float* sb = src + (size_t)b * DCH * (HWDIM * HWDIM);
#pragma unroll 4
    for (int k = 0; k < 32; ++k) {
        int j = t + 256 * k;
        int c = j >> 5, s = j & 31;
        tile[c][s] = sb[(size_t)c * (HWDIM * HWDIM) + s0 + s];
    }
    __syncthreads();
    int p = t & 127;
    int srow = t >> 7;
    if (isf1) {
        _Float16* db = f1h + ((size_t)b * 6400 + s0) * DCH;
#pragma unroll 4
        for (int k = 0; k < 16; ++k) {
            int s = 2 * k + srow;
            h2 v;
            v[0] = (_Float16)tile[2 * p][s];
            v[1] = (_Float16)tile[2 * p + 1][s];
            *(h2*)(db + (size_t)s * DCH + 2 * p) = v;
        }
    } else {
#pragma unroll 4
        for (int k = 0; k < 16; ++k) {
            int s = 2 * k + srow;
            int spatial = s0 + s;
            int yy = spatial / 80;
            int xx = spatial - yy * 80;
            h2 v;
            v[0] = (_Float16)tile[2 * p][s];
            v[1] = (_Float16)tile[2 * p + 1][s];
            size_t off = (size_t)b * 2073600 + (size_t)(p >> 4) * 259200
                       + ((size_t)(yy + 5) * 90 + (xx + 5)) * 32 + ((2 * p) & 31);
            *(h2*)(f2p0 + off) = v;
        }
    }
}

// ---------- all pools from L0 directly: L1 2x2, L2 4x4, L3 8x8 ----------
__global__ __launch_bounds__(256) void pools(const _Float16* __restrict__ l0,
                                             _Float16* __restrict__ l1,
                                             _Float16* __restrict__ l2,
                                             _Float16* __restrict__ l3) {
    int i = blockIdx.x * 256 + threadIdx.x;      // 409600 + 102400 + 25600 = 537600
    if (i < 409600) {
        int c2 = i & 15;
        int r = i >> 4;
        int x = r % 40; r /= 40;
        int y = r % 40; r /= 40;
        int pl = r & 7;
        int b = r >> 3;
        const h2* s = (const h2*)l0 + (size_t)b * 1036800 + (size_t)pl * 129600
                    + ((size_t)(2 * y + 5) * 90 + (2 * x + 5)) * 16 + c2;
        h2 v00 = s[0], v01 = s[16], v10 = s[90 * 16], v11 = s[90 * 16 + 16];
        float r0 = ((float)v00[0] + (float)v01[0] + (float)v10[0] + (float)v11[0]) * 0.25f;
        float r1 = ((float)v00[1] + (float)v01[1] + (float)v10[1] + (float)v11[1]) * 0.25f;
        h2 o; o[0] = (_Float16)r0; o[1] = (_Float16)r1;
        *((h2*)l1 + (size_t)b * 320000 + (size_t)pl * 40000
          + ((size_t)(y + 5) * 50 + (x + 5)) * 16 + c2) = o;
    } else if (i < 512000) {
        int j = i - 409600;
        int c2 = j & 15;
        int r = j >> 4;
        int x = r % 20; r /= 20;
        int y = r % 20; r /= 20;
        int pl = r & 7;
        int b = r >> 3;
        const h2* s = (const h2*)l0 + (size_t)b * 1036800 + (size_t)pl * 129600 + c2;
        float r0 = 0.f, r1 = 0.f;
#pragma unroll
        for (int dy = 0; dy < 4; ++dy)
#pragma unroll
            for (int dx = 0; dx < 4; ++dx) {
                h2 v = s[((size_t)(4 * y + dy + 5) * 90 + (4 * x + dx + 5)) * 16];
                r0 += (float)v[0];
                r1 += (float)v[1];
            }
        h2 o; o[0] = (_Float16)(r0 * 0.0625f); o[1] = (_Float16)(r1 * 0.0625f);
        *((h2*)l2 + (size_t)b * 115200 + (size_t)pl * 14400
          + ((size_t)(y + 5) * 30 + (x + 5)) * 16 + c2) = o;
    } else {
        int j = i - 512000;
        int c2 = j & 15;
        int r = j >> 4;
        int x = r % 10; r /= 10;
        int y = r % 10; r /= 10;
        int pl = r & 7;
        int b = r >> 3;
        const h2* s = (const h2*)l0 + (size_t)b * 1036800 + (size_t)pl * 129600 + c2;
        float r0 = 0.f, r1 = 0.f;
#pragma unroll
        for (int dy = 0; dy < 8; ++dy)
#pragma unroll
            for (int dx = 0; dx < 8; ++dx) {
                h2 v = s[((size_t)(8 * y + dy + 5) * 90 + (8 * x + dx + 5)) * 16];
                r0 += (float)v[0];
                r1 += (float)v[1];
            }
        h2 o; o[0] = (_Float16)(r0 * 0.015625f); o[1] = (_Float16)(r1 * 0.015625f);
        *((h2*)l3 + (size_t)b * 51200 + (size_t)pl * 6400
          + ((size_t)(y + 5) * 20 + (x + 5)) * 16 + c2) = o;
    }
}

// ---------- single-block bucket sort (4x4 cells, pad 16) ----------
static __device__ __forceinline__ int bucket_of(const float* coords, int n) {
    int b = n / 6400;
    int r = n - b * 6400;
    float cx = coords[(size_t)b * 12800 + r];
    float cy = coords[(size_t)b * 12800 + 6400 + r];
    int ix = min(max((int)floorf(cx), 0), 79);
    int iy = min(max((int)floorf(cy), 0), 79);
    return b * 400 + (iy >> 2) * 20 + (ix >> 2);
}

__global__ __launch_bounds__(1024) void bucket_k(const float* __restrict__ coords,
                                                 int* __restrict__ sortedIdxP,
                                                 int* __restrict__ rank) {
    __shared__ unsigned int histS[NBUCKET], startS[NBUCKET], curS[NBUCKET];
    __shared__ unsigned int waveSum[16];
    __shared__ unsigned int totalS;
    int t = threadIdx.x;
    if (t < NBUCKET) histS[t] = 0u;
    __syncthreads();
    int bkt[13];
#pragma unroll
    for (int i = 0; i < 13; ++i) {
        int n = i * 1024 + t;
        if (n < NPIX) {
            bkt[i] = bucket_of(coords, n);
            atomicAdd(&histS[bkt[i]], 1u);
        }
    }
    __syncthreads();
    unsigned int v = (t < NBUCKET) ? ((histS[t] + 15u) & ~15u) : 0u;
    unsigned int x = v;
#pragma unroll
    for (int d = 1; d < 64; d <<= 1) {
        unsigned int y = __shfl_up(x, d);
        if ((t & 63) >= d) x += y;
    }
    if ((t & 63) == 63) waveSum[t >> 6] = x;
    __syncthreads();
    if (t < 16) {
        unsigned int w = waveSum[t];
#pragma unroll
        for (int d = 1; d < 16; d <<= 1) {
            unsigned int y = __shfl_up(w, d);
            if (t >= d) w += y;
        }
        waveSum[t] = w;
    }
    __syncthreads();
    unsigned int incl = x + ((t >> 6) ? waveSum[(t >> 6) - 1] : 0u);
    if (t < NBUCKET) {
        unsigned int e = incl - v;
        startS[t] = e;
        curS[t] = e;
        if (t == NBUCKET - 1) totalS = incl;
    }
    __syncthreads();
#pragma unroll
    for (int i = 0; i < 13; ++i) {
        int n = i * 1024 + t;
        if (n < NPIX) {
            unsigned int pos = atomicAdd(&curS[bkt[i]], 1u);
            sortedIdxP[pos] = n;
            rank[n] = (int)pos;
        }
    }
    __syncthreads();
    if (t < NBUCKET) {
        unsigned int h = histS[t];
        if (h) {
            unsigned int pc = (h + 15u) & ~15u;
            unsigned int base = startS[t];
            int dup = sortedIdxP[base];
            for (unsigned int s = h; s < pc; ++s) sortedIdxP[base + s] = dup;
        }
    }
    for (unsigned int s = totalS + t; s < 25600u; s += 1024u) sortedIdxP[s] = -1;
}

// ---------- stage one k-plane of the level window into LDS (coalesced) ----------
// LDS slot s (16B) holds row r=s>>2, chunk (s&3)^(r&3) (XOR swizzle, involution).
template <int L>
static __device__ __forceinline__ void stage_plane(int tid, int wave, int kk,
                                                   const _Float16* __restrict__ f2b,
                                                   char* buf) {
    const int Ww = L == 0 ? 13 : L == 1 ? 11 : 10;
    const int MT = L == 0 ? 169 : L == 1 ? 121 : 100;
    const int MAG = L == 0 ? 161320 : L == 1 ? 190652 : 209716;
    const int Wp = L == 0 ? 90 : L == 1 ? 50 : L == 2 ? 30 : 20;
    const int PSB = 2 * (L == 0 ? 259200 : L == 1 ? 80000 : L == 2 ? 28800 : 12800);
    const int NS = MT * 4;
#pragma unroll
    for (int p = 0; p < (NS + 511) / 512; ++p) {
        int s = p * 512 + tid;
        if (s < NS) {
            int r = s >> 2, c = s & 3;
            int my = (r * MAG) >> 21;
            int mx = r - my * Ww;
            int cc = c ^ (r & 3);
            const char* g = (const char*)f2b + (my * Wp + mx) * 64 + cc * 16 + kk * PSB;
            char* l = buf + (p * 512 + wave * 64) * 16;   // wave-uniform base
            __builtin_amdgcn_global_load_lds(
                (const __attribute__((address_space(1))) void*)g,
                (__attribute__((address_space(3))) void*)l, 16, 0, 0);
        }
    }
}

// ---------- one pyramid level: 8 k-planes, dbuf staging, acc in regs ----------
template <int L>
static __device__ __forceinline__ void run_level(
    int tid, int lane, int wave, int b,
    const _Float16* __restrict__ f2pL,
    const int* X0cS, const int* Y0cS,
    const float (*fxS)[16], const float (*fyS)[16],
    const int (*lxS)[16], const int (*lyS)[16],
    const _Float16* f1S, char (*planeB)[176 * 64], _Float16* G,
    _Float16* __restrict__ sc) {
    const int Ww = L == 0 ? 13 : L == 1 ? 11 : 10;
    const int NT = L == 0 ? 11 : L == 1 ? 8 : 7;
    const int MT = L == 0 ? 169 : L == 1 ? 121 : 100;
    const int Wp = L == 0 ? 90 : L == 1 ? 50 : L == 2 ? 30 : 20;
    const int PB = L == 0 ? 2073600 : L == 1 ? 640000 : L == 2 ? 230400 : 102400;
    const _Float16* f2b = f2pL + (size_t)b * PB
                        + ((size_t)(Y0cS[L] + 5) * Wp + (X0cS[L] + 5)) * 32;
    bool has0 = wave < NT;
    bool has1 = (wave + 8) < NT;
    int ch = lane >> 4;
    int r0 = min(wave * 16 + (lane & 15), MT - 1);
    int r1 = min((wave + 8) * 16 + (lane & 15), MT - 1);
    int la0 = (r0 * 4 + (ch ^ (r0 & 3))) * 16;   // swizzled LDS byte addr
    int la1 = (r1 * 4 + (ch ^ (r1 & 3))) * 16;

    f32x4 acc0 = {0.f, 0.f, 0.f, 0.f};
    f32x4 acc1 = {0.f, 0.f, 0.f, 0.f};
    stage_plane<L>(tid, wave, 0, f2b, planeB[0]);
    __syncthreads();                               // drains vmcnt before barrier
#pragma unroll
    for (int kk = 0; kk < 8; ++kk) {
        if (kk < 7) stage_plane<L>(tid, wave, kk + 1, f2b, planeB[(kk + 1) & 1]);
        half8 bfk = *(const half8*)(f1S + (lane & 15) * 264 + (ch + 4 * kk) * 8);
        const char* pb = planeB[kk & 1];
        if (has0) {
            half8 a0 = *(const half8*)(pb + la0);
            acc0 = __builtin_amdgcn_mfma_f32_16x16x32_f16(a0, bfk, acc0, 0, 0, 0);
        }
        if (has1) {
            half8 a1 = *(const half8*)(pb + la1);
            acc1 = __builtin_amdgcn_mfma_f32_16x16x32_f16(a1, bfk, acc1, 0, 0, 0);
        }
        __syncthreads();
    }
    if (has0) {
        int gr = wave * 16 + ch * 4;
#pragma unroll
        for (int r = 0; r < 4; ++r) G[(gr + r) * 17 + (lane & 15)] = (_Float16)acc0[r];
    }
    if (has1) {
        int gr = (wave + 8) * 16 + ch * 4;
#pragma unroll
        for (int r = 0; r < 4; ++r) G[(gr + r) * 17 + (lane & 15)] = (_Float16)acc1[r];
    }
    __syncthreads();
    // epilogue for this level: 16 px x 81 taps
    for (int idx = tid; idx < 16 * 81; idx += 512) {
        int x = (idx * 12946) >> 20;          // idx/81, exact for idx<1296
        int k = idx - x * 81;
        int a = (k * 57) >> 9;                // k/9
        int c = k - 9 * a;
        int gx = lxS[L][x] + a, gy = lyS[L][x] + c;
        int m00 = gy * Ww + gx;
        float fx = fxS[L][x], fy = fyS[L][x];
        float t00 = (float)G[m00 * 17 + x];
        float t01 = (float)G[(m00 + 1) * 17 + x];
        float t10 = (float)G[(m00 + Ww) * 17 + x];
        float t11 = (float)G[(m00 + Ww + 1) * 17 + x];
        float v = ((1.f - fy) * ((1.f - fx) * t00 + fx * t01)
                 + fy * ((1.f - fx) * t10 + fx * t11)) * 0.0625f;
        sc[x * CHP + L * 81 + k] = (_Float16)v;
    }
    // next level's prologue barrier protects G/plane reuse
}

// ---------- main: per-bucket gather-GEMM, staged A operand ----------
__global__ __launch_bounds__(512, 8) void corr_mfma(
    const _Float16* __restrict__ f1h,
    const _Float16* __restrict__ f2p0, const _Float16* __restrict__ f2p1,
    const _Float16* __restrict__ f2p2, const _Float16* __restrict__ f2p3,
    const float* __restrict__ coords, const int* __restrict__ sortedIdxP,
    _Float16* __restrict__ scratch) {
    __shared__ __align__(16) char planeB[2][176 * 64];   // 22.0 KB
    __shared__ _Float16 G[176 * 17];                     //  6.0 KB
    __shared__ _Float16 f1S[16 * 264];                   //  8.25 KB
    __shared__ float fxS[4][16], fyS[4][16];
    __shared__ int lxS[4][16], lyS[4][16];
    __shared__ int X0cS[4], Y0cS[4], bS;

    int pphys = blockIdx.x;
    int l = (pphys & 7) * 200 + (pphys >> 3);   // XCD swizzle, 1600 % 8 == 0
    int tid = threadIdx.x;
    if (sortedIdxP[l * 16] < 0) return;
    int lane = tid & 63;
    int wave = tid >> 6;

    // stage f1 block: 16 px x 512 B, one coalesced pass by all 512 threads
    {
        int px = tid >> 5, q = tid & 31;
        int n = sortedIdxP[l * 16 + px];
        const float4* src = (const float4*)(f1h + (size_t)n * DCH);
        *((float4*)(f1S + px * 264) + q) = src[q];
    }
    if (tid < 64) {
        int px = tid & 15, Lt = tid >> 4;
        int n = sortedIdxP[l * 16 + px];
        int b = n / 6400;
        int r = n - b * 6400;
        float cx = coords[(size_t)b * 12800 + r];
        float cy = coords[(size_t)b * 12800 + 6400 + r];
        float ls = 1.0f / (float)(1 << Lt);
        float cxl = cx * ls, cyl = cy * ls;
        float fxf = floorf(cxl), fyf = floorf(cyl);
        int X0 = (int)fxf - 4, Y0 = (int)fyf - 4;
        int ix = min(max((int)floorf(cx), 0), 79);
        int iy = min(max((int)floorf(cy), 0), 79);
        int X0c = (((ix >> 2) * 4) >> Lt) - 4;
        int Y0c = (((iy >> 2) * 4) >> Lt) - 4;
        lxS[Lt][px] = min(max(X0 - X0c, 0), 3);
        lyS[Lt][px] = min(max(Y0 - Y0c, 0), 3);
        fxS[Lt][px] = cxl - fxf;
        fyS[Lt][px] = cyl - fyf;
        X0cS[Lt] = X0c;
        Y0cS[Lt] = Y0c;
        if (tid == 0) bS = sortedIdxP[l * 16] / 6400;
    }
    __syncthreads();
    int b = bS;
    _Float16* sc = scratch + (size_t)l * 16 * CHP;

    run_level<0>(tid, lane, wave, b, f2p0, X0cS, Y0cS, fxS, fyS, lxS, lyS, f1S, planeB, G, sc);
    run_level<1>(tid, lane, wave, b, f2p1, X0cS, Y0cS, fxS, fyS, lxS, lyS, f1S, planeB, G, sc);
    run_level<2>(tid, lane, wave, b, f2p2, X0cS, Y0cS, fxS, fyS, lxS, lyS, f1S, planeB, G, sc);
    run_level<3>(tid, lane, wave, b, f2p3, X0cS, Y0cS, fxS, fyS, lxS, lyS, f1S, planeB, G, sc);
}

// ---------- unsort: gather full 64B lines, LDS transpose, coalesced writes ----
__global__ __launch_bounds__(256) void unsort_t(const _Float16* __restrict__ scratch,
                                                const int* __restrict__ rank,
                                                float* __restrict__ out) {
    __shared__ _Float16 lds[64][40];
    int blk = blockIdx.x;
    int b = blk / 100;
    int nl0 = (blk % 100) * 64;
    int t = threadIdx.x;
    int p = t >> 2, j = t & 3;
    int n = blk * 64 + p;
    int rk = rank[n];
    const float4* src = (const float4*)(scratch + (size_t)rk * CHP);
    int px = t & 63, iq = t >> 6;

    for (int c = 0; c < 11; ++c) {
        float4 f4 = src[c * 4 + j];
        *(float4*)(&lds[p][j * 8]) = f4;
        __syncthreads();
#pragma unroll
        for (int w = 0; w < 8; ++w) {
            int i = w * 4 + iq;
            int ch = c * 32 + i;
            if (ch < 324)
                out[((size_t)b * 324 + ch) * 6400 + nl0 + px] = (float)lds[px][i];
        }
        __syncthreads();
    }
}

extern "C" void kernel_launch(void* const* d_in, const int* in_sizes, int n_in,
                              void* d_out, int out_size, void* d_ws, size_t ws_size,
                              hipStream_t stream) {
    const float* fmap1 = (const float*)d_in[0];
    const float* fmap2 = (const float*)d_in[1];
    const float* coords = (const float*)d_in[2];
    float* out = (float*)d_out;
    char* ws = (char*)d_ws;

    _Float16* f1h  = (_Float16*)(ws);                  //  6,553,600
    _Float16* f2p0 = (_Float16*)(ws + 6553600);        //  8,294,400 (K-plane, pad 5)
    _Float16* f2p1 = (_Float16*)(ws + 14848000);       //  2,560,000
    _Float16* f2p2 = (_Float16*)(ws + 17408000);       //    921,600
    _Float16* f2p3 = (_Float16*)(ws + 18329600);       //    409,600
    int* sortedIdxP = (int*)(ws + 18739200);           //    102,400 (25600 ints)
    int* rank       = (int*)(ws + 18841600);           //     51,200
    _Float16* scratch = (_Float16*)(ws + 18892800);    // 25600*352*2 = 18,022,400

    zero_k<<<dim3(2975), dim3(256), 0, stream>>>((float4*)f2p0);

    transpose_all<<<dim3(800), dim3(256), 0, stream>>>(fmap1, fmap2, f1h, f2p0);
    pools<<<dim3(2100), dim3(256), 0, stream>>>(f2p0, f2p1, f2p2, f2p3);
    bucket_k<<<dim3(1), dim3(1024), 0, stream>>>(coords, sortedIdxP, rank);
    corr_mfma<<<dim3(1600), dim3(512), 0, stream>>>(f1h, f2p0, f2p1, f2p2, f2p3,
                                                    coords, sortedIdxP, scratch);
    unsort_t<<<dim3(200), dim3(256), 0, stream>>>(scratch, rank, out);
}